// Round 9
// baseline (114.917 us; speedup 1.0000x reference)
//
#include <hip/hip_runtime.h>
#include <hip/hip_fp16.h>
#include <hip/hip_cooperative_groups.h>
#include <cstdint>

namespace cg = cooperative_groups;

typedef __attribute__((ext_vector_type(8))) _Float16 f16x8;
typedef __attribute__((ext_vector_type(4))) float f32x4;
typedef __attribute__((ext_vector_type(16))) float f32x16;

__device__ __forceinline__ f16x8 cvt8(float4 x, float4 y) {
    f16x8 r;
    r[0] = (_Float16)x.x; r[1] = (_Float16)x.y; r[2] = (_Float16)x.z; r[3] = (_Float16)x.w;
    r[4] = (_Float16)y.x; r[5] = (_Float16)y.y; r[6] = (_Float16)y.z; r[7] = (_Float16)y.w;
    return r;
}

__device__ __forceinline__ f16x8 relu8(f16x8 v) {
    f16x8 z = {};
    return __builtin_elementwise_max(v, z);   // v_pk_max_f16
}

// ============ mega: phaseA (xpose) -> sync -> phaseB (prep GEMMs) -> sync -> phaseC (fused) ====
// grid = 256 blocks x 512 thr, 1 block/CU, cooperative.
__global__ __launch_bounds__(512, 1)
void mega(const float* __restrict__ query, const float* __restrict__ prot,
          const float* __restrict__ W1, const float* __restrict__ b1,
          const float* __restrict__ W2, const float* __restrict__ b2,
          const float* __restrict__ W3,
          _Float16* __restrict__ qh16, _Float16* __restrict__ w1t,
          uint4* __restrict__ w2p, _Float16* __restrict__ phpk,
          float* __restrict__ sqp, float* __restrict__ q2,
          float* __restrict__ Gm, float* __restrict__ out)
{
    __shared__ union SMem {
        struct { _Float16 lt[2][64][73]; } a;                                     // 18.7 KB
        struct { uint4 w2l[4352]; float w3l[128]; float spart[2][2][2][128]; } c; // 76.6 KB
    } sm;

    cg::grid_group grid = cg::this_grid();
    const int t = threadIdx.x;

    // ---------------- Phase A: W1 transpose->f16, W2ext pack, Gram, ||q||^2 ----------------
    {
        int u = (int)blockIdx.x * 2 + (t >> 8);     // 2 units of 256 thr per block
        int tt = t & 255;
        if (u < 32) {
            _Float16 (*lt)[73] = sm.a.lt[t >> 8];
            int bi = u >> 2, bj = u & 3;
            int r0 = bi * 64, c0 = bj * 64;
            #pragma unroll
            for (int it = 0; it < 4; ++it) {
                int row = it * 16 + (tt >> 4);
                int c4 = (tt & 15) * 4;
                float4 v = *(const float4*)(W1 + (r0 + row) * 256 + c0 + c4);
                lt[row][c4]     = (_Float16)v.x;
                lt[row][c4 + 1] = (_Float16)v.y;
                lt[row][c4 + 2] = (_Float16)v.z;
                lt[row][c4 + 3] = (_Float16)v.w;
            }
            __syncthreads();                        // blocks 0..15: all 512 threads reach this
            int c = tt >> 2, kq = tt & 3;
            unsigned short o[16];
            #pragma unroll
            for (int i = 0; i < 16; ++i) {
                union { _Float16 f; unsigned short s; } uu;
                uu.f = lt[kq * 16 + i][c];
                o[i] = uu.s;
            }
            _Float16* dst = w1t + (r0 >= 256 ? 65536 : 0) + (c0 + c) * 256 + (r0 & 255) + kq * 16;
            *(uint4*)dst       = *(uint4*)&o[0];
            *(uint4*)(dst + 8) = *(uint4*)&o[8];
        } else if (u < 49) {
            int chunk = (u - 32) * 256 + tt;        // 0..4351
            int ks = chunk >> 8, h = (chunk >> 7) & 1, c = chunk & 127;
            f16x8 o = {};
            if (ks < 16) {
                #pragma unroll
                for (int j = 0; j < 8; ++j)
                    o[j] = (_Float16)W2[(ks * 16 + h * 8 + j) * 128 + c];
            } else if (h == 0) {
                o[0] = (_Float16)b2[c];
            }
            ((f16x8*)w2p)[chunk] = o;
        } else if (u < 81) {
            int pid = (u - 49) * 32 + (tt >> 3), l8 = tt & 7;
            int c = pid >> 6, k = (pid >> 3) & 7, kp = pid & 7;
            const float4* pa = (const float4*)(prot + (c * 8 + k) * 256 + l8 * 32);
            const float4* pb = (const float4*)(prot + (c * 8 + kp) * 256 + l8 * 32);
            float s = 0.f;
            #pragma unroll
            for (int i = 0; i < 8; ++i) {
                float4 x = pa[i], y = pb[i];
                s += x.x * y.x + x.y * y.y + x.z * y.z + x.w * y.w;
            }
            s += __shfl_xor(s, 1); s += __shfl_xor(s, 2); s += __shfl_xor(s, 4);
            if (l8 == 0) Gm[pid] = s;
        } else if (u < 145) {
            int m = (u - 81) * 32 + (tt >> 3), l8 = tt & 7;
            const float4* qp = (const float4*)(query + m * 256 + l8 * 32);
            float s = 0.f;
            #pragma unroll
            for (int i = 0; i < 8; ++i) {
                float4 x = qp[i];
                s += x.x * x.x + x.y * x.y + x.z * x.z + x.w * x.w;
            }
            s += __shfl_xor(s, 1); s += __shfl_xor(s, 2); s += __shfl_xor(s, 4);
            if (l8 == 0) q2[m] = s;
        }
    }

    grid.sync();

    // ---------------- Phase B: MFMA prep GEMMs (qh16 / sqp / phpk), 200 half-units ----------
    {
        int hu = (int)blockIdx.x * 2 + (t >> 8);
        if (hu < 200) {
            int tt = t & 255;
            int w = tt >> 6, l = tt & 63, l15 = l & 15, l4 = l >> 4;
            int mode, row0, col0;
            if (hu < 128)      { mode = 0; row0 = (hu >> 2) * 64;         col0 = (hu & 3) * 64; }
            else if (hu < 192) { mode = 1; row0 = ((hu - 128) >> 1) * 64; col0 = ((hu - 128) & 1) * 64; }
            else               { mode = 2; row0 = ((hu - 192) >> 2) * 64; col0 = ((hu - 192) & 3) * 64; }
            const float* Asrc = (mode == 2) ? prot : query;
            const _Float16* Bsrc = (mode == 2) ? (w1t + 65536) : w1t;

            f32x4 acc[4];
            #pragma unroll
            for (int nt = 0; nt < 4; ++nt) acc[nt] = (f32x4){0.f, 0.f, 0.f, 0.f};

            for (int ks = 0; ks < 8; ++ks) {
                int row = row0 + w * 16 + l15;
                const float* ap = Asrc + row * 256 + ks * 32 + l4 * 8;
                f16x8 af = cvt8(*(const float4*)ap, *(const float4*)(ap + 4));
                f16x8 bf[4];
                #pragma unroll
                for (int nt = 0; nt < 4; ++nt) {
                    int col = col0 + nt * 16 + l15;
                    if (mode == 1) {
                        const float* bp = prot + col * 256 + ks * 32 + l4 * 8;
                        bf[nt] = cvt8(*(const float4*)bp, *(const float4*)(bp + 4));
                    } else {
                        bf[nt] = *(const f16x8*)(Bsrc + col * 256 + ks * 32 + l4 * 8);
                    }
                }
                #pragma unroll
                for (int nt = 0; nt < 4; ++nt)
                    acc[nt] = __builtin_amdgcn_mfma_f32_16x16x32_f16(af, bf[nt], acc[nt], 0, 0, 0);
            }
            #pragma unroll
            for (int nt = 0; nt < 4; ++nt)
                #pragma unroll
                for (int j = 0; j < 4; ++j) {
                    int row = row0 + w * 16 + l4 * 4 + j;
                    int col = col0 + nt * 16 + l15;
                    float v = acc[nt][j];
                    if (mode == 0)      qh16[row * 256 + col] = (_Float16)v;
                    else if (mode == 1) sqp[row * 128 + col] = v;
                    else                phpk[(((col >> 4) * 2 + ((col >> 3) & 1)) * 128 + row) * 8
                                             + (col & 7)] = (_Float16)(v + b1[col]);
                }
        }
    }

    grid.sync();

    // ---------------- Phase C: fused 32x32x16 MFMA + softmax + Gram distance ----------------
    {
        uint4* w2l = sm.c.w2l;
        float* w3l = sm.c.w3l;

        int wid = t >> 6, l = t & 63;
        int rg = wid & 3, cs = wid >> 2;
        int lk = l & 31, h = l >> 5;
        int ck = rg * 32 + lk;

        for (int i = t; i < 4352; i += 512) w2l[i] = w2p[i];
        if (t < 128) w3l[t] = W3[t];

        f16x8 ph[16];
        #pragma unroll
        for (int ks = 0; ks < 16; ++ks)
            ph[ks] = *(const f16x8*)(phpk + ((ks * 2 + h) * 128 + ck) * 8);

        __syncthreads();

        const _Float16* w2lh = (const _Float16*)w2l;
        int m0 = blockIdx.x * 8;

        for (int mi = 0; mi < 4; ++mi) {
            int mA = m0 + mi * 2;
            const _Float16* qra = qh16 + mA * 256 + h * 8;
            const _Float16* qrb = qra + 256;

            f32x16 acc[2][2];
            #pragma unroll
            for (int mm = 0; mm < 2; ++mm)
                #pragma unroll
                for (int ct = 0; ct < 2; ++ct) acc[mm][ct] = (f32x16){};

            f16x8 qa[4], qb[4];
            #pragma unroll
            for (int p = 0; p < 4; ++p) {
                qa[p] = *(const f16x8*)(qra + p * 16);
                qb[p] = *(const f16x8*)(qrb + p * 16);
            }

            #pragma unroll
            for (int ks = 0; ks < 16; ++ks) {
                f16x8 aA = relu8(qa[ks & 3] + ph[ks]);
                f16x8 aB = relu8(qb[ks & 3] + ph[ks]);
                if (ks < 12) {
                    qa[ks & 3] = *(const f16x8*)(qra + (ks + 4) * 16);
                    qb[ks & 3] = *(const f16x8*)(qrb + (ks + 4) * 16);
                }
                #pragma unroll
                for (int ct = 0; ct < 2; ++ct) {
                    f16x8 bfr = *(const f16x8*)(w2lh + ((ks * 2 + h) * 128 + cs * 64 + ct * 32 + lk) * 8);
                    acc[0][ct] = __builtin_amdgcn_mfma_f32_32x32x16_f16(bfr, aA, acc[0][ct], 0, 0, 0);
                    acc[1][ct] = __builtin_amdgcn_mfma_f32_32x32x16_f16(bfr, aB, acc[1][ct], 0, 0, 0);
                }
            }
            {   // K-extension step: adds b2 (A'ext = b2, B'ext = 1)
                f16x8 e = {};
                if (h == 0) e[0] = (_Float16)1.0f;
                #pragma unroll
                for (int ct = 0; ct < 2; ++ct) {
                    f16x8 bfr = *(const f16x8*)(w2lh + ((32 + h) * 128 + cs * 64 + ct * 32 + lk) * 8);
                    acc[0][ct] = __builtin_amdgcn_mfma_f32_32x32x16_f16(bfr, e, acc[0][ct], 0, 0, 0);
                    acc[1][ct] = __builtin_amdgcn_mfma_f32_32x32x16_f16(bfr, e, acc[1][ct], 0, 0, 0);
                }
            }

            int buf = mi & 1;
            #pragma unroll
            for (int mm = 0; mm < 2; ++mm) {
                float s = 0.f;
                #pragma unroll
                for (int ct = 0; ct < 2; ++ct)
                    #pragma unroll
                    for (int r = 0; r < 16; ++r)
                        s = fmaf(fmaxf(acc[mm][ct][r], 0.f),
                                 w3l[cs * 64 + ct * 32 + (r & 3) + 8 * (r >> 2) + 4 * h], s);
                s += __shfl_xor(s, 32);
                if (l < 32) sm.c.spart[buf][mm][cs][ck] = s;
            }
            __syncthreads();

            if (t < 256) {
                int msel = t >> 7, ckk = t & 127, kk = t & 7;
                int m = mA + msel;
                int c = ckk >> 3;
                float s = sm.c.spart[buf][msel][0][ckk] + sm.c.spart[buf][msel][1][ckk];
                float mx = s;
                mx = fmaxf(mx, __shfl_xor(mx, 1));
                mx = fmaxf(mx, __shfl_xor(mx, 2));
                mx = fmaxf(mx, __shfl_xor(mx, 4));
                float e = __expf(s - mx);
                float den = e;
                den += __shfl_xor(den, 1); den += __shfl_xor(den, 2); den += __shfl_xor(den, 4);
                float a = e / den;
                float p2 = a * sqp[m * 128 + ckk];
                float p3 = 0.f;
                #pragma unroll
                for (int kq = 0; kq < 8; ++kq) {
                    float ak = __shfl(a, (l & 56) | kq);
                    p3 = fmaf(ak, Gm[c * 64 + kq * 8 + kk], p3);
                }
                p3 *= a;
                float pr = p3 - 2.f * p2;
                pr += __shfl_xor(pr, 1); pr += __shfl_xor(pr, 2); pr += __shfl_xor(pr, 4);
                if (kk == 0)
                    out[m * 16 + c] = -sqrtf(fmaxf(q2[m] + pr, 0.f));
            }
        }
    }
}

extern "C" void kernel_launch(void* const* d_in, const int* in_sizes, int n_in,
                              void* d_out, int out_size, void* d_ws, size_t ws_size,
                              hipStream_t stream) {
    const float* query = (const float*)d_in[0];
    const float* prot  = (const float*)d_in[1];
    const float* W1    = (const float*)d_in[2];
    const float* b1    = (const float*)d_in[3];
    const float* W2    = (const float*)d_in[4];
    const float* b2    = (const float*)d_in[5];
    const float* W3    = (const float*)d_in[6];
    // b3 (d_in[7]): constant pre-softmax shift -> softmax-invariant: unused.

    char* ws = (char*)d_ws;
    _Float16* qh16 = (_Float16*)(ws);                 // 2048*256*2 = 1048576
    _Float16* w1t  = (_Float16*)(ws + 1048576);       // 512*256*2  = 262144
    uint4*    w2p  = (uint4*)(ws + 1310720);          // 4352*16    = 69632
    _Float16* phpk = (_Float16*)(ws + 1380352);       // 128*256*2  = 65536
    float*    sqp  = (float*)(ws + 1445888);          // 2048*128*4 = 1048576
    float*    q2   = (float*)(ws + 2494464);          // 2048*4     = 8192
    float*    Gm   = (float*)(ws + 2502656);          // 1024*4     = 4096
    float*    out  = (float*)d_out;

    void* args[] = { (void*)&query, (void*)&prot, (void*)&W1, (void*)&b1,
                     (void*)&W2, (void*)&b2, (void*)&W3,
                     (void*)&qh16, (void*)&w1t, (void*)&w2p, (void*)&phpk,
                     (void*)&sqp, (void*)&q2, (void*)&Gm, (void*)&out };
    (void)hipLaunchCooperativeKernel((const void*)mega, dim3(256), dim3(512), args, 0, stream);
}